// Round 1
// baseline (1609.498 us; speedup 1.0000x reference)
//
#include <hip/hip_runtime.h>

// GCN 2-layer + mean pool.
// Layout of d_ws:
//   [0 .. N*4)              : int cnt[N] -> float deg_inv_sqrt[N] (in place)
//   [off1 .. off1+N*64*4)   : bufA
//   [off1+N*64*4 .. )       : bufB

__global__ void count_deg_kernel(const int* __restrict__ dst, int* __restrict__ cnt, int e) {
    int i = blockIdx.x * blockDim.x + threadIdx.x;
    int stride = gridDim.x * blockDim.x;
    for (; i < e; i += stride) {
        atomicAdd(&cnt[dst[i]], 1);
    }
}

__global__ void make_dis_kernel(const int* cnt, float* dis, int n) {
    int i = blockIdx.x * blockDim.x + threadIdx.x;
    if (i < n) {
        float d = (float)cnt[i] + 1.0f;   // +1 self loop
        dis[i] = rsqrtf(d);
    }
}

// C[n x 64] = A[n x K] @ B[K x 64]; optionally also writes AGG = C * dis^2 (self-loop init).
template <int K, bool FUSE>
__global__ __launch_bounds__(256)
void gemm_kernel(const float* __restrict__ A, const float* __restrict__ B,
                 const float* __restrict__ dis, float* __restrict__ H,
                 float* __restrict__ AGG, int n) {
    constexpr int KP = K + 4;                 // pad: breaks LDS bank aliasing
    __shared__ float As[64 * KP];
    __shared__ float Bs[K * 64];
    const int tid = threadIdx.x;
    const int row0 = blockIdx.x * 64;

    // Stage A tile (64 x K), zero-fill tail rows.
    constexpr int A4 = 64 * (K / 4);
    for (int idx = tid; idx < A4; idx += 256) {
        int row = idx / (K / 4);
        int c4  = idx % (K / 4);
        float4 v = make_float4(0.f, 0.f, 0.f, 0.f);
        int r = row0 + row;
        if (r < n) v = *reinterpret_cast<const float4*>(A + (size_t)r * K + c4 * 4);
        *reinterpret_cast<float4*>(&As[row * KP + c4 * 4]) = v;
    }
    // Stage B (K x 64).
    constexpr int B4 = K * 16;
    for (int idx = tid; idx < B4; idx += 256) {
        int row = idx / 16, c4 = idx % 16;
        *reinterpret_cast<float4*>(&Bs[row * 64 + c4 * 4]) =
            *reinterpret_cast<const float4*>(B + row * 64 + c4 * 4);
    }
    __syncthreads();

    const int tr = tid >> 4;   // 0..15 -> rows tr*4..tr*4+3
    const int tc = tid & 15;   // 0..15 -> cols tc*4..tc*4+3
    float acc[4][4];
#pragma unroll
    for (int j = 0; j < 4; ++j)
#pragma unroll
        for (int i = 0; i < 4; ++i) acc[j][i] = 0.f;

    for (int k4 = 0; k4 < K / 4; ++k4) {
        float4 a[4], b[4];
#pragma unroll
        for (int j = 0; j < 4; ++j)
            a[j] = *reinterpret_cast<const float4*>(&As[(tr * 4 + j) * KP + k4 * 4]);
#pragma unroll
        for (int kk = 0; kk < 4; ++kk)
            b[kk] = *reinterpret_cast<const float4*>(&Bs[(k4 * 4 + kk) * 64 + tc * 4]);
#pragma unroll
        for (int kk = 0; kk < 4; ++kk) {
#pragma unroll
            for (int j = 0; j < 4; ++j) {
                float av = (kk == 0) ? a[j].x : (kk == 1) ? a[j].y : (kk == 2) ? a[j].z : a[j].w;
                acc[j][0] = fmaf(av, b[kk].x, acc[j][0]);
                acc[j][1] = fmaf(av, b[kk].y, acc[j][1]);
                acc[j][2] = fmaf(av, b[kk].z, acc[j][2]);
                acc[j][3] = fmaf(av, b[kk].w, acc[j][3]);
            }
        }
    }

#pragma unroll
    for (int j = 0; j < 4; ++j) {
        int r = row0 + tr * 4 + j;
        if (r < n) {
            float4 v = make_float4(acc[j][0], acc[j][1], acc[j][2], acc[j][3]);
            *reinterpret_cast<float4*>(H + (size_t)r * 64 + tc * 4) = v;
            if (FUSE) {
                float ds = dis[r];
                float s = ds * ds;
                float4 w = make_float4(v.x * s, v.y * s, v.z * s, v.w * s);
                *reinterpret_cast<float4*>(AGG + (size_t)r * 64 + tc * 4) = w;
            }
        }
    }
}

// One wave per edge (grid-stride): lane c handles channel c.
__global__ __launch_bounds__(256)
void scatter_kernel(const int* __restrict__ src, const int* __restrict__ dst,
                    const float* __restrict__ dis, const float* __restrict__ h,
                    float* __restrict__ agg, int e) {
    const int lane = threadIdx.x & 63;
    int wave = blockIdx.x * (blockDim.x >> 6) + (threadIdx.x >> 6);
    const int nwaves = gridDim.x * (blockDim.x >> 6);
    for (int ed = wave; ed < e; ed += nwaves) {
        int s = src[ed];
        int d = dst[ed];
        float norm = dis[s] * dis[d];
        float v = h[(size_t)s * 64 + lane] * norm;
        atomicAdd(&agg[(size_t)d * 64 + lane], v);
    }
}

// out = relu(agg + bias)  (float4 over n*16)
__global__ void bias_relu_kernel(const float* __restrict__ agg, const float* __restrict__ b,
                                 float* __restrict__ out, int total4) {
    int idx = blockIdx.x * blockDim.x + threadIdx.x;
    int stride = gridDim.x * blockDim.x;
    for (; idx < total4; idx += stride) {
        float4 v = reinterpret_cast<const float4*>(agg)[idx];
        const float4 bb = *reinterpret_cast<const float4*>(b + (idx & 15) * 4);
        v.x = fmaxf(v.x + bb.x, 0.f);
        v.y = fmaxf(v.y + bb.y, 0.f);
        v.z = fmaxf(v.z + bb.z, 0.f);
        v.w = fmaxf(v.w + bb.w, 0.f);
        reinterpret_cast<float4*>(out)[idx] = v;
    }
}

// agg = h * dis[row]^2  (float4 over n*16)
__global__ void self_init_kernel(const float* __restrict__ h, const float* __restrict__ dis,
                                 float* __restrict__ agg, int total4) {
    int idx = blockIdx.x * blockDim.x + threadIdx.x;
    int stride = gridDim.x * blockDim.x;
    for (; idx < total4; idx += stride) {
        int row = idx >> 4;
        float ds = dis[row];
        float s = ds * ds;
        float4 v = reinterpret_cast<const float4*>(h)[idx];
        v.x *= s; v.y *= s; v.z *= s; v.w *= s;
        reinterpret_cast<float4*>(agg)[idx] = v;
    }
}

// mean over nodes of relu(agg + b2) -> out[64]
__global__ __launch_bounds__(256)
void finalize_kernel(const float* __restrict__ agg, const float* __restrict__ b,
                     float* __restrict__ out, int n) {
    __shared__ float lds[256];
    const int tid = threadIdx.x;
    float acc = 0.f;
    const int total = n * 64;
    for (int i = blockIdx.x * 256 + tid; i < total; i += gridDim.x * 256) {
        float v = agg[i] + b[i & 63];
        acc += fmaxf(v, 0.f);
    }
    lds[tid] = acc;
    __syncthreads();
    if (tid < 64) {
        float s = lds[tid] + lds[tid + 64] + lds[tid + 128] + lds[tid + 192];
        atomicAdd(&out[tid], s / (float)n);
    }
}

extern "C" void kernel_launch(void* const* d_in, const int* in_sizes, int n_in,
                              void* d_out, int out_size, void* d_ws, size_t ws_size,
                              hipStream_t stream) {
    const float* x  = (const float*)d_in[0];
    const int*   ei = (const int*)d_in[1];
    const float* W1 = (const float*)d_in[2];
    const float* b1 = (const float*)d_in[3];
    const float* W2 = (const float*)d_in[4];
    const float* b2 = (const float*)d_in[5];

    const int n = in_sizes[0] / 128;   // 100000
    const int e = in_sizes[1] / 2;     // 3200000
    const int* src = ei;
    const int* dst = ei + e;

    char* ws = (char*)d_ws;
    float* dis = (float*)ws;
    size_t off1 = (((size_t)n * 4) + 1023) & ~(size_t)1023;
    float* bufA = (float*)(ws + off1);
    float* bufB = (float*)(ws + off1 + (size_t)n * 64 * 4);

    hipMemsetAsync(dis, 0, (size_t)n * 4, stream);
    hipMemsetAsync(d_out, 0, 64 * sizeof(float), stream);

    count_deg_kernel<<<2048, 256, 0, stream>>>(dst, (int*)dis, e);
    make_dis_kernel<<<(n + 255) / 256, 256, 0, stream>>>((const int*)dis, dis, n);

    const int gblocks = (n + 63) / 64;
    // Layer 1: h1 = x@W1 -> bufA; agg1 init = h1*dis^2 -> bufB (fused)
    gemm_kernel<128, true><<<gblocks, 256, 0, stream>>>(x, W1, dis, bufA, bufB, n);
    scatter_kernel<<<2048, 256, 0, stream>>>(src, dst, dis, bufA, bufB, e);
    // x2 = relu(agg1 + b1) -> bufA
    bias_relu_kernel<<<1024, 256, 0, stream>>>(bufB, b1, bufA, n * 16);
    // Layer 2: h2 = x2@W2 -> bufB
    gemm_kernel<64, false><<<gblocks, 256, 0, stream>>>(bufA, W2, dis, bufB, nullptr, n);
    // agg2 init = h2*dis^2 -> bufA (x2 dead now)
    self_init_kernel<<<1024, 256, 0, stream>>>(bufB, dis, bufA, n * 16);
    scatter_kernel<<<2048, 256, 0, stream>>>(src, dst, dis, bufB, bufA, e);
    // out = mean_n relu(agg2 + b2)
    finalize_kernel<<<1024, 256, 0, stream>>>(bufA, b2, (float*)d_out, n);
}

// Round 2
// 890.505 us; speedup vs baseline: 1.8074x; 1.8074x over previous
//
#include <hip/hip_runtime.h>

// GCN 2-layer + mean pool, CSR-gather formulation (no f32 atomics).
//
// ws layout:
//   dis[N] f32 | cnt[N] int (becomes cursor) | rowptr[N+1] int | bsum[1024] int
//   csr_src[E] int | csr_norm[E] f32 | bufA[N*64] f32 | bufB[N*64] f32

__global__ void count_deg_kernel(const int* __restrict__ dst, int* __restrict__ cnt, int e) {
    int i = blockIdx.x * blockDim.x + threadIdx.x;
    int stride = gridDim.x * blockDim.x;
    for (; i < e; i += stride) atomicAdd(&cnt[dst[i]], 1);
}

__global__ void make_dis_kernel(const int* __restrict__ cnt, float* __restrict__ dis, int n) {
    int i = blockIdx.x * blockDim.x + threadIdx.x;
    if (i < n) dis[i] = rsqrtf((float)cnt[i] + 1.0f);   // +1 self loop
}

// --- exclusive scan of cnt -> rowptr (and cursor copy) ---
__global__ void scan1_kernel(const int* __restrict__ cnt, int* __restrict__ bsum, int n) {
    __shared__ int lds[256];
    int t = threadIdx.x;
    int i = blockIdx.x * 256 + t;
    lds[t] = (i < n) ? cnt[i] : 0;
    __syncthreads();
    for (int off = 128; off > 0; off >>= 1) {
        if (t < off) lds[t] += lds[t + off];
        __syncthreads();
    }
    if (t == 0) bsum[blockIdx.x] = lds[0];
}

__global__ void scan2_kernel(int* __restrict__ bsum, int nb) {
    if (threadIdx.x == 0 && blockIdx.x == 0) {
        int run = 0;
        for (int b = 0; b < nb; ++b) { int v = bsum[b]; bsum[b] = run; run += v; }
    }
}

__global__ void scan3_kernel(const int* __restrict__ cnt, const int* __restrict__ bsum,
                             int* __restrict__ rowptr, int* __restrict__ cursor, int n) {
    __shared__ int lds[256];
    int t = threadIdx.x;
    int i = blockIdx.x * 256 + t;
    int c = (i < n) ? cnt[i] : 0;
    lds[t] = c;
    __syncthreads();
    for (int off = 1; off < 256; off <<= 1) {
        int v = (t >= off) ? lds[t - off] : 0;
        __syncthreads();
        lds[t] += v;
        __syncthreads();
    }
    if (i < n) {
        int base = bsum[blockIdx.x];
        int ex = base + lds[t] - c;
        rowptr[i] = ex;
        cursor[i] = ex;
        if (i == n - 1) rowptr[n] = base + lds[t];
    }
}

__global__ void fill_csr_kernel(const int* __restrict__ src, const int* __restrict__ dst,
                                const float* __restrict__ dis, int* __restrict__ cursor,
                                int* __restrict__ csr_src, float* __restrict__ csr_norm, int e) {
    int i = blockIdx.x * blockDim.x + threadIdx.x;
    int stride = gridDim.x * blockDim.x;
    for (; i < e; i += stride) {
        int s = src[i], d = dst[i];
        int pos = atomicAdd(&cursor[d], 1);
        csr_src[pos] = s;
        csr_norm[pos] = dis[s] * dis[d];
    }
}

// C[n x 64] = A[n x K] @ B[K x 64]
template <int K>
__global__ __launch_bounds__(256)
void gemm_kernel(const float* __restrict__ A, const float* __restrict__ B,
                 float* __restrict__ H, int n) {
    constexpr int KP = K + 4;
    __shared__ float As[64 * KP];
    __shared__ float Bs[K * 64];
    const int tid = threadIdx.x;
    const int row0 = blockIdx.x * 64;

    constexpr int A4 = 64 * (K / 4);
    for (int idx = tid; idx < A4; idx += 256) {
        int row = idx / (K / 4);
        int c4  = idx % (K / 4);
        float4 v = make_float4(0.f, 0.f, 0.f, 0.f);
        int r = row0 + row;
        if (r < n) v = *reinterpret_cast<const float4*>(A + (size_t)r * K + c4 * 4);
        *reinterpret_cast<float4*>(&As[row * KP + c4 * 4]) = v;
    }
    constexpr int B4 = K * 16;
    for (int idx = tid; idx < B4; idx += 256) {
        int row = idx / 16, c4 = idx % 16;
        *reinterpret_cast<float4*>(&Bs[row * 64 + c4 * 4]) =
            *reinterpret_cast<const float4*>(B + row * 64 + c4 * 4);
    }
    __syncthreads();

    const int tr = tid >> 4;
    const int tc = tid & 15;
    float acc[4][4];
#pragma unroll
    for (int j = 0; j < 4; ++j)
#pragma unroll
        for (int i = 0; i < 4; ++i) acc[j][i] = 0.f;

    for (int k4 = 0; k4 < K / 4; ++k4) {
        float4 a[4], b[4];
#pragma unroll
        for (int j = 0; j < 4; ++j)
            a[j] = *reinterpret_cast<const float4*>(&As[(tr * 4 + j) * KP + k4 * 4]);
#pragma unroll
        for (int kk = 0; kk < 4; ++kk)
            b[kk] = *reinterpret_cast<const float4*>(&Bs[(k4 * 4 + kk) * 64 + tc * 4]);
#pragma unroll
        for (int kk = 0; kk < 4; ++kk) {
#pragma unroll
            for (int j = 0; j < 4; ++j) {
                float av = (kk == 0) ? a[j].x : (kk == 1) ? a[j].y : (kk == 2) ? a[j].z : a[j].w;
                acc[j][0] = fmaf(av, b[kk].x, acc[j][0]);
                acc[j][1] = fmaf(av, b[kk].y, acc[j][1]);
                acc[j][2] = fmaf(av, b[kk].z, acc[j][2]);
                acc[j][3] = fmaf(av, b[kk].w, acc[j][3]);
            }
        }
    }

#pragma unroll
    for (int j = 0; j < 4; ++j) {
        int r = row0 + tr * 4 + j;
        if (r < n) {
            float4 v = make_float4(acc[j][0], acc[j][1], acc[j][2], acc[j][3]);
            *reinterpret_cast<float4*>(H + (size_t)r * 64 + tc * 4) = v;
        }
    }
}

// One wave per dst node (grid-stride). lane = channel.
// acc = sum_{j->i} norm_j * h[src_j] + dis_i^2 * h[i]; val = relu(acc + bias).
// WRITE_OUT: store per-node val. Else: fold into channel-wise mean (atomicAdd per block).
template <bool WRITE_OUT>
__global__ __launch_bounds__(256)
void agg_kernel(const int* __restrict__ rowptr, const int* __restrict__ csr_src,
                const float* __restrict__ csr_norm, const float* __restrict__ h,
                const float* __restrict__ dis, const float* __restrict__ bias,
                float* __restrict__ out, float* __restrict__ outsum,
                int n, float inv_n) {
    const int lane = threadIdx.x & 63;
    const int wid  = blockIdx.x * 4 + (threadIdx.x >> 6);
    const int nw   = gridDim.x * 4;
    const float b = bias[lane];
    float bsum = 0.f;

    for (int node = wid; node < n; node += nw) {
        const int st = rowptr[node];
        const int en = rowptr[node + 1];
        const float ds = dis[node];
        float acc = h[node * 64 + lane] * ds * ds;
        int e = st;
        for (; e + 1 < en; e += 2) {
            int s0 = csr_src[e], s1 = csr_src[e + 1];
            float n0 = csr_norm[e], n1 = csr_norm[e + 1];
            float v0 = h[s0 * 64 + lane];
            float v1 = h[s1 * 64 + lane];
            acc = fmaf(v0, n0, acc);
            acc = fmaf(v1, n1, acc);
        }
        if (e < en) acc = fmaf(h[csr_src[e] * 64 + lane], csr_norm[e], acc);
        float val = fmaxf(acc + b, 0.f);
        if (WRITE_OUT) out[node * 64 + lane] = val;
        else bsum += val;
    }

    if (!WRITE_OUT) {
        __shared__ float lds[256];
        lds[threadIdx.x] = bsum;
        __syncthreads();
        if (threadIdx.x < 64) {
            float s = lds[threadIdx.x] + lds[threadIdx.x + 64] +
                      lds[threadIdx.x + 128] + lds[threadIdx.x + 192];
            atomicAdd(&outsum[threadIdx.x], s * inv_n);
        }
    }
}

extern "C" void kernel_launch(void* const* d_in, const int* in_sizes, int n_in,
                              void* d_out, int out_size, void* d_ws, size_t ws_size,
                              hipStream_t stream) {
    const float* x  = (const float*)d_in[0];
    const int*   ei = (const int*)d_in[1];
    const float* W1 = (const float*)d_in[2];
    const float* b1 = (const float*)d_in[3];
    const float* W2 = (const float*)d_in[4];
    const float* b2 = (const float*)d_in[5];

    const int n = in_sizes[0] / 128;   // 100000
    const int e = in_sizes[1] / 2;     // 3200000
    const int* src = ei;
    const int* dst = ei + e;

    char* ws = (char*)d_ws;
    size_t off = 0;
    auto alloc = [&](size_t bytes) { void* p = ws + off; off = (off + bytes + 255) & ~(size_t)255; return p; };
    float* dis     = (float*)alloc((size_t)n * 4);
    int*   cnt     = (int*)  alloc((size_t)n * 4);       // later reused as cursor
    int*   rowptr  = (int*)  alloc((size_t)(n + 1) * 4);
    int*   bsum    = (int*)  alloc(1024 * 4);
    int*   csr_src = (int*)  alloc((size_t)e * 4);
    float* csr_nrm = (float*)alloc((size_t)e * 4);
    float* bufA    = (float*)alloc((size_t)n * 64 * 4);
    float* bufB    = (float*)alloc((size_t)n * 64 * 4);

    hipMemsetAsync(cnt, 0, (size_t)n * 4, stream);
    hipMemsetAsync(d_out, 0, 64 * sizeof(float), stream);

    const int nb = (n + 255) / 256;

    count_deg_kernel<<<2048, 256, 0, stream>>>(dst, cnt, e);
    make_dis_kernel<<<nb, 256, 0, stream>>>(cnt, dis, n);
    scan1_kernel<<<nb, 256, 0, stream>>>(cnt, bsum, n);
    scan2_kernel<<<1, 64, 0, stream>>>(bsum, nb);
    scan3_kernel<<<nb, 256, 0, stream>>>(cnt, bsum, rowptr, cnt /*cursor*/, n);
    fill_csr_kernel<<<2048, 256, 0, stream>>>(src, dst, dis, cnt, csr_src, csr_nrm, e);

    const int gblocks = (n + 63) / 64;
    // Layer 1: h1 = x@W1 -> bufA
    gemm_kernel<128><<<gblocks, 256, 0, stream>>>(x, W1, bufA, n);
    // x2 = relu(agg(h1) + b1) -> bufB
    agg_kernel<true><<<2048, 256, 0, stream>>>(rowptr, csr_src, csr_nrm, bufA, dis, b1,
                                               bufB, nullptr, n, 0.f);
    // Layer 2: h2 = x2@W2 -> bufA
    gemm_kernel<64><<<gblocks, 256, 0, stream>>>(bufB, W2, bufA, n);
    // out = mean_n relu(agg(h2) + b2)  (no per-node materialization)
    agg_kernel<false><<<2048, 256, 0, stream>>>(rowptr, csr_src, csr_nrm, bufA, dis, b2,
                                                nullptr, (float*)d_out, n, 1.0f / (float)n);
}

// Round 3
// 877.554 us; speedup vs baseline: 1.8341x; 1.0148x over previous
//
#include <hip/hip_runtime.h>

// GCN 2-layer + mean pool, CSR-gather formulation (no f32 atomics, no csr_norm).
//
// ws layout:
//   dis[N] f32 | cnt[N] int (becomes cursor) | rowptr[N+1] int | bsum[512] int
//   csr_src[E] int | bufA[N*64] f32 | bufB[N*64] f32

__global__ void count_deg_kernel(const int* __restrict__ dst, int* __restrict__ cnt, int e) {
    int i = blockIdx.x * blockDim.x + threadIdx.x;
    int stride = gridDim.x * blockDim.x;
    for (; i < e; i += stride) atomicAdd(&cnt[dst[i]], 1);
}

__global__ void make_dis_kernel(const int* __restrict__ cnt, float* __restrict__ dis, int n) {
    int i = blockIdx.x * blockDim.x + threadIdx.x;
    if (i < n) dis[i] = rsqrtf((float)cnt[i] + 1.0f);   // +1 self loop
}

// --- exclusive scan of cnt -> rowptr (and cursor copy) ---
__global__ void scan1_kernel(const int* __restrict__ cnt, int* __restrict__ bsum, int n) {
    __shared__ int lds[256];
    int t = threadIdx.x;
    int i = blockIdx.x * 256 + t;
    lds[t] = (i < n) ? cnt[i] : 0;
    __syncthreads();
    for (int off = 128; off > 0; off >>= 1) {
        if (t < off) lds[t] += lds[t + off];
        __syncthreads();
    }
    if (t == 0) bsum[blockIdx.x] = lds[0];
}

// Single-block parallel exclusive scan over block sums (nb <= 512).
__global__ __launch_bounds__(512)
void scan2_kernel(int* __restrict__ bsum, int nb) {
    __shared__ int lds[512];
    int t = threadIdx.x;
    int v = (t < nb) ? bsum[t] : 0;
    lds[t] = v;
    __syncthreads();
    for (int off = 1; off < 512; off <<= 1) {
        int add = (t >= off) ? lds[t - off] : 0;
        __syncthreads();
        lds[t] += add;
        __syncthreads();
    }
    if (t < nb) bsum[t] = lds[t] - v;   // exclusive
}

__global__ void scan3_kernel(const int* __restrict__ cnt, const int* __restrict__ bsum,
                             int* __restrict__ rowptr, int* __restrict__ cursor, int n) {
    __shared__ int lds[256];
    int t = threadIdx.x;
    int i = blockIdx.x * 256 + t;
    int c = (i < n) ? cnt[i] : 0;
    lds[t] = c;
    __syncthreads();
    for (int off = 1; off < 256; off <<= 1) {
        int v = (t >= off) ? lds[t - off] : 0;
        __syncthreads();
        lds[t] += v;
        __syncthreads();
    }
    if (i < n) {
        int base = bsum[blockIdx.x];
        int ex = base + lds[t] - c;
        rowptr[i] = ex;
        cursor[i] = ex;
        if (i == n - 1) rowptr[n] = base + lds[t];
    }
}

// Counting-sort placement: only csr_src (4 B/edge scattered).
__global__ void fill_csr_kernel(const int* __restrict__ src, const int* __restrict__ dst,
                                int* __restrict__ cursor, int* __restrict__ csr_src, int e) {
    int i = blockIdx.x * blockDim.x + threadIdx.x;
    int stride = gridDim.x * blockDim.x;
    for (; i < e; i += stride) {
        int s = src[i], d = dst[i];
        int pos = atomicAdd(&cursor[d], 1);
        csr_src[pos] = s;
    }
}

// C[n x 64] = A[n x K] @ B[K x 64]
template <int K>
__global__ __launch_bounds__(256)
void gemm_kernel(const float* __restrict__ A, const float* __restrict__ B,
                 float* __restrict__ H, int n) {
    constexpr int KP = K + 4;
    __shared__ float As[64 * KP];
    __shared__ float Bs[K * 64];
    const int tid = threadIdx.x;
    const int row0 = blockIdx.x * 64;

    constexpr int A4 = 64 * (K / 4);
    for (int idx = tid; idx < A4; idx += 256) {
        int row = idx / (K / 4);
        int c4  = idx % (K / 4);
        float4 v = make_float4(0.f, 0.f, 0.f, 0.f);
        int r = row0 + row;
        if (r < n) v = *reinterpret_cast<const float4*>(A + (size_t)r * K + c4 * 4);
        *reinterpret_cast<float4*>(&As[row * KP + c4 * 4]) = v;
    }
    constexpr int B4 = K * 16;
    for (int idx = tid; idx < B4; idx += 256) {
        int row = idx / 16, c4 = idx % 16;
        *reinterpret_cast<float4*>(&Bs[row * 64 + c4 * 4]) =
            *reinterpret_cast<const float4*>(B + row * 64 + c4 * 4);
    }
    __syncthreads();

    const int tr = tid >> 4;
    const int tc = tid & 15;
    float acc[4][4];
#pragma unroll
    for (int j = 0; j < 4; ++j)
#pragma unroll
        for (int i = 0; i < 4; ++i) acc[j][i] = 0.f;

    for (int k4 = 0; k4 < K / 4; ++k4) {
        float4 a[4], b[4];
#pragma unroll
        for (int j = 0; j < 4; ++j)
            a[j] = *reinterpret_cast<const float4*>(&As[(tr * 4 + j) * KP + k4 * 4]);
#pragma unroll
        for (int kk = 0; kk < 4; ++kk)
            b[kk] = *reinterpret_cast<const float4*>(&Bs[(k4 * 4 + kk) * 64 + tc * 4]);
#pragma unroll
        for (int kk = 0; kk < 4; ++kk) {
#pragma unroll
            for (int j = 0; j < 4; ++j) {
                float av = (kk == 0) ? a[j].x : (kk == 1) ? a[j].y : (kk == 2) ? a[j].z : a[j].w;
                acc[j][0] = fmaf(av, b[kk].x, acc[j][0]);
                acc[j][1] = fmaf(av, b[kk].y, acc[j][1]);
                acc[j][2] = fmaf(av, b[kk].z, acc[j][2]);
                acc[j][3] = fmaf(av, b[kk].w, acc[j][3]);
            }
        }
    }

#pragma unroll
    for (int j = 0; j < 4; ++j) {
        int r = row0 + tr * 4 + j;
        if (r < n) {
            float4 v = make_float4(acc[j][0], acc[j][1], acc[j][2], acc[j][3]);
            *reinterpret_cast<float4*>(H + (size_t)r * 64 + tc * 4) = v;
        }
    }
}

// One wave per dst node (grid-stride). lane = channel.
// acc = sum_{j->i} dis[s_j]*dis[i] * h[s_j] + dis_i^2 * h[i]; val = relu(acc + bias).
template <bool WRITE_OUT>
__global__ __launch_bounds__(256)
void agg_kernel(const int* __restrict__ rowptr, const int* __restrict__ csr_src,
                const float* __restrict__ h, const float* __restrict__ dis,
                const float* __restrict__ bias,
                float* __restrict__ out, float* __restrict__ outsum,
                int n, float inv_n) {
    const int lane = threadIdx.x & 63;
    const int wid  = blockIdx.x * 4 + (threadIdx.x >> 6);
    const int nw   = gridDim.x * 4;
    const float b = bias[lane];
    float bsum = 0.f;

    for (int node = wid; node < n; node += nw) {
        const int st = rowptr[node];
        const int en = rowptr[node + 1];
        const float ds = dis[node];
        float acc = h[node * 64 + lane] * ds * ds;
        int e = st;
        for (; e + 1 < en; e += 2) {
            int s0 = csr_src[e], s1 = csr_src[e + 1];
            float n0 = dis[s0] * ds, n1 = dis[s1] * ds;
            float v0 = h[s0 * 64 + lane];
            float v1 = h[s1 * 64 + lane];
            acc = fmaf(v0, n0, acc);
            acc = fmaf(v1, n1, acc);
        }
        if (e < en) {
            int s0 = csr_src[e];
            acc = fmaf(h[s0 * 64 + lane], dis[s0] * ds, acc);
        }
        float val = fmaxf(acc + b, 0.f);
        if (WRITE_OUT) out[node * 64 + lane] = val;
        else bsum += val;
    }

    if (!WRITE_OUT) {
        __shared__ float lds[256];
        lds[threadIdx.x] = bsum;
        __syncthreads();
        if (threadIdx.x < 64) {
            float s = lds[threadIdx.x] + lds[threadIdx.x + 64] +
                      lds[threadIdx.x + 128] + lds[threadIdx.x + 192];
            atomicAdd(&outsum[threadIdx.x], s * inv_n);
        }
    }
}

extern "C" void kernel_launch(void* const* d_in, const int* in_sizes, int n_in,
                              void* d_out, int out_size, void* d_ws, size_t ws_size,
                              hipStream_t stream) {
    const float* x  = (const float*)d_in[0];
    const int*   ei = (const int*)d_in[1];
    const float* W1 = (const float*)d_in[2];
    const float* b1 = (const float*)d_in[3];
    const float* W2 = (const float*)d_in[4];
    const float* b2 = (const float*)d_in[5];

    const int n = in_sizes[0] / 128;   // 100000
    const int e = in_sizes[1] / 2;     // 3200000
    const int* src = ei;
    const int* dst = ei + e;

    char* ws = (char*)d_ws;
    size_t off = 0;
    auto alloc = [&](size_t bytes) { void* p = ws + off; off = (off + bytes + 255) & ~(size_t)255; return p; };
    float* dis     = (float*)alloc((size_t)n * 4);
    int*   cnt     = (int*)  alloc((size_t)n * 4);       // later reused as cursor
    int*   rowptr  = (int*)  alloc((size_t)(n + 1) * 4);
    int*   bsum    = (int*)  alloc(512 * 4);
    int*   csr_src = (int*)  alloc((size_t)e * 4);
    float* bufA    = (float*)alloc((size_t)n * 64 * 4);
    float* bufB    = (float*)alloc((size_t)n * 64 * 4);

    hipMemsetAsync(cnt, 0, (size_t)n * 4, stream);
    hipMemsetAsync(d_out, 0, 64 * sizeof(float), stream);

    const int nb = (n + 255) / 256;   // 391 (<= 512 required by scan2)

    count_deg_kernel<<<2048, 256, 0, stream>>>(dst, cnt, e);
    make_dis_kernel<<<nb, 256, 0, stream>>>(cnt, dis, n);
    scan1_kernel<<<nb, 256, 0, stream>>>(cnt, bsum, n);
    scan2_kernel<<<1, 512, 0, stream>>>(bsum, nb);
    scan3_kernel<<<nb, 256, 0, stream>>>(cnt, bsum, rowptr, cnt /*cursor*/, n);
    fill_csr_kernel<<<2048, 256, 0, stream>>>(src, dst, cnt, csr_src, e);

    const int gblocks = (n + 63) / 64;
    // Layer 1: h1 = x@W1 -> bufA
    gemm_kernel<128><<<gblocks, 256, 0, stream>>>(x, W1, bufA, n);
    // x2 = relu(agg(h1) + b1) -> bufB
    agg_kernel<true><<<2048, 256, 0, stream>>>(rowptr, csr_src, bufA, dis, b1,
                                               bufB, nullptr, n, 0.f);
    // Layer 2: h2 = x2@W2 -> bufA
    gemm_kernel<64><<<gblocks, 256, 0, stream>>>(bufB, W2, bufA, n);
    // out = mean_n relu(agg(h2) + b2)  (no per-node materialization)
    agg_kernel<false><<<2048, 256, 0, stream>>>(rowptr, csr_src, bufA, dis, b2,
                                                nullptr, (float*)d_out, n, 1.0f / (float)n);
}